// Round 19
// baseline (1809.978 us; speedup 1.0000x reference)
//
#include <hip/hip_runtime.h>

// Problem constants (fixed by the reference).
#define TSTEPS 256
#define NNODE  100000
#define NEDGE  8192

constexpr float MU_P  = 0.1f;
constexpr float MU_M  = 0.05f;
constexpr float RHO_  = 16.0f;
constexpr float CLO   = 1e-5f;
constexpr float CHI   = 1.0f - 1e-5f;
constexpr float SCALE = 1048576.0f;          // 2^20 fixed-point for delta
constexpr float INVSC = 1.0f / 1048576.0f;

#define SENT32 0xFFFFFFFFu
typedef unsigned long long u64;

__device__ __forceinline__ float sigm(float x) {
  return 1.0f / (1.0f + __expf(-x));
}
__device__ __forceinline__ float x0_of(const float* logit, int n) {
  return fminf(fmaxf(sigm(logit[n]), CLO), CHI);
}
__device__ __forceinline__ int edge_at(const int* __restrict__ arr, int idx,
                                       int is64) {
  if (is64) return (int)((const long long*)arr)[idx];
  return arr[idx];
}
__device__ __forceinline__ u64 pload(const u64* p) {
  return __hip_atomic_load(p, __ATOMIC_RELAXED, __HIP_MEMORY_SCOPE_WORKGROUP);
}
// FIX (R18 post-mortem): pair updates must be MONOTONE IN TAG. Two plain
// stores to the same pair from different XCDs (B1 {t0,...} vs B2 {t1,...})
// leave two dirty L2 copies with UNDEFINED writeback order -> {t0} could
// overwrite {t1}, and the next dispatch's catch-up then skips delta(t0)
// (error ~ 0.086, deterministic -- exactly R16-R18's failure). atomicMax on
// the u64 {tag:32|val:32} serializes at the coherence point: the tag can
// never go backwards, regardless of write order. Duplicate same-tag writers
// carry identical bits.
__device__ __forceinline__ void pmax(u64* p, u64 v) {
  atomicMax(p, v);
}
__device__ __forceinline__ float clipf(float x) {
  return fminf(fmaxf(x, CLO), CHI);
}

// R11-proven agent-scope primitives (MALL coherence point, cross-XCD).
__device__ __forceinline__ unsigned agent_load_u32(const unsigned* p) {
  return __hip_atomic_load(p, __ATOMIC_RELAXED, __HIP_MEMORY_SCOPE_AGENT);
}
__device__ __forceinline__ unsigned agent_fadd_u32(unsigned* p, unsigned v) {
  return __hip_atomic_fetch_add(p, v, __ATOMIC_RELAXED,
                                __HIP_MEMORY_SCOPE_AGENT);
}

// phase-1 lazy (R12-proven): pair plain + dprev plain, both issued together.
__device__ __forceinline__ float lazy2(const u64* xs64,
                                       const unsigned* __restrict__ dP,
                                       int n, unsigned t0) {
  const u64 a = pload(&xs64[n]);
  const int acc = (int)dP[n];
  const unsigned tag = (unsigned)(a >> 32);
  const float pv = __uint_as_float((unsigned)a);
  const float cu = clipf(pv + (float)acc * INVSC);
  return (tag == t0) ? pv : cu;
}

// phase-2 lazy: self-correcting under pair-write visibility races; delta(t0)
// read AGENT (MALL). All fallback paths produce identical bits.
__device__ __forceinline__ float lazy3(const u64* xs64,
                                       const unsigned* __restrict__ dP,
                                       const unsigned* __restrict__ dA,
                                       int n, unsigned t0) {
  const u64 a = pload(&xs64[n]);
  const unsigned tag = (unsigned)(a >> 32);
  const float val = __uint_as_float((unsigned)a);
  if (tag == t0 + 1u) return val;                    // B2's write (x_{t1})
  float v1;
  if (tag == t0) {
    v1 = val;                                        // B1's write (x_{t0})
  } else {
    v1 = clipf(val + (float)((int)dP[n]) * INVSC);   // catch-up via dprev
  }
  const int acc1 = (int)agent_load_u32(&dA[n]);      // MALL read of delta(t0)
  return clipf(v1 + (float)acc1 * INVSC);
}

// ---------------------------------------------------------------------------
// k_init: pairs {tag0, clip(sigmoid)}; ws delta buffers zero; flags+bar zero;
// outX row 0 + sentinel rows 1..T-1. Re-runs every call -> deterministic.
// ---------------------------------------------------------------------------
__global__ void k_init(const float* __restrict__ logit,
                       const int* __restrict__ u, const int* __restrict__ v,
                       u64* __restrict__ xs64,
                       unsigned* __restrict__ b0, unsigned* __restrict__ b1,
                       unsigned* __restrict__ b2,
                       unsigned* __restrict__ dflags,
                       float* __restrict__ outX) {
  const int i = blockIdx.x * blockDim.x + threadIdx.x;
  const int stride = gridDim.x * blockDim.x;

  if (i == 0) {   // int width probe + barrier reset
    const unsigned* a = (const unsigned*)u;
    const unsigned* b = (const unsigned*)v;
    bool i64 = true;
    for (int k = 1; k < 128; k += 2) i64 = i64 && (a[k] == 0u) && (b[k] == 0u);
    dflags[0] = i64 ? 1u : 0u;
    dflags[4] = 0u;                                  // bar
  }

  for (int n = i; n < NNODE; n += stride) {
    xs64[n] = (u64)__float_as_uint(x0_of(logit, n)); // tag 0
    b0[n] = 0u;
    b1[n] = 0u;
    b2[n] = 0u;
    outX[n] = sigm(logit[n]);                        // row 0, unclipped
  }
  unsigned* outX32 = (unsigned*)outX;
  const int total = TSTEPS * NNODE;
  for (int w = NNODE + i; w < total; w += stride) outX32[w] = SENT32;
}

// ---------------------------------------------------------------------------
// k_prep: int32 ids + premultiplied weights into outX-tail scratch; zero the
// two scratch delta buffers (B3, B4) living there too.
// ---------------------------------------------------------------------------
__global__ void k_prep(const int* __restrict__ u, const int* __restrict__ v,
                       const float* __restrict__ sp, const float* __restrict__ sm,
                       int* __restrict__ uv32u, int* __restrict__ uv32v,
                       float* __restrict__ wsc,
                       unsigned* __restrict__ b3, unsigned* __restrict__ b4,
                       const unsigned* __restrict__ dflags) {
  const int g = blockIdx.x * blockDim.x + threadIdx.x;
  const int stride = gridDim.x * blockDim.x;
  const int is64 = (int)dflags[0];
  for (int e = g; e < TSTEPS * NEDGE; e += stride) {
    uv32u[e] = edge_at(u, e, is64);
    uv32v[e] = edge_at(v, e, is64);
    wsc[e] = (MU_P * sp[e] - MU_M * sm[e]) * SCALE;
  }
  for (int n = g; n < NNODE; n += stride) {
    b3[n] = 0u;
    b4[n] = 0u;
  }
}

// ---------------------------------------------------------------------------
// k_step2: TWO timesteps (t0=2d, t1=2d+1) per dispatch. 160 blocks x 256.
//  Phase 1: [0,32) A1: edges row t0 -> AGENT returning fetch_add into dA
//           (results kept alive -> vmcnt-drain == performed at MALL) -> bar
//           arrive. [32,96) B1: apply row t0-1 via atomicMax pair write.
//           [96,160) C: zero next dispatch's two buffers, exit.
//  Barrier: spin on agent LOAD of bar (target=32*(d+1)).
//  Phase 2: [0,32) A2: edges row t1 via lazy3 -> plain adds into dB;
//           [32,96) B2: apply row t0 via lazy3, atomicMax pair {t1,val}.
// Pair writes are atomicMax -> tag-monotone regardless of B1/B2 order or
// XCD writeback order (the R16-R18 bug). Readers self-correct on staleness.
// ---------------------------------------------------------------------------
__global__ __launch_bounds__(256) void k_step2(
    const int* __restrict__ uv32u, const int* __restrict__ uv32v,
    const float* __restrict__ wsc,
    u64* __restrict__ xs64,
    unsigned* __restrict__ dA, unsigned* __restrict__ dB,
    const unsigned* __restrict__ dP,
    unsigned* __restrict__ dz1, unsigned* __restrict__ dz2,
    float* __restrict__ cvals,
    unsigned* __restrict__ bar, unsigned target, int t0) {
  const int bid = blockIdx.x;
  const int tid = threadIdx.x;
  const unsigned ut0 = (unsigned)t0;
  const int t1 = t0 + 1;

  if (bid >= 96) {
    // ---- C: dense-zero the two buffers used by the NEXT dispatch ----
    const int base = (bid - 96) * 256 + tid;
    for (int n = base; n < NNODE; n += 64 * 256) {
      dz1[n] = 0u;
      dz2[n] = 0u;
    }
    return;
  }

  if (bid < 32) {
    // ---- A1: edges of row t0 ----
    const int i = bid * 256 + tid;
    const int eA = t0 * NEDGE + i;
    const int unA = uv32u[eA];
    const int vnA = uv32v[eA];
    const float wA = wsc[eA];
    const float xu = lazy2(xs64, dP, unA, ut0);
    const float xv = lazy2(xs64, dP, vnA, ut0);
    const int iv = __float2int_rn(wA * (xv - xu));
    const unsigned o1 = agent_fadd_u32(&dA[unA], (unsigned)iv);
    const unsigned o2 = agent_fadd_u32(&dA[vnA], (unsigned)(-iv));
    asm volatile("" :: "v"(o1), "v"(o2));
    __syncthreads();                 // vmcnt(0): adds performed at MALL
    if (tid == 0) {
      const unsigned o3 = agent_fadd_u32(&bar[0], 1u);
      asm volatile("" :: "v"(o3));
    }
  } else {
    // ---- B1: apply endpoints of row t0-1 (tag-monotone pair write) ----
    if (t0 >= 1) {
      const int j = (bid - 32) * 256 + tid;
      const int e2 = (t0 - 1) * NEDGE + (j < NEDGE ? j : j - NEDGE);
      const int node = (j < NEDGE) ? uv32u[e2] : uv32v[e2];
      const float val = lazy2(xs64, dP, node, ut0);
      pmax(&xs64[node], ((u64)ut0 << 32) | (u64)__float_as_uint(val));
      cvals[(size_t)(t0 - 1) * (2 * NEDGE) + j] = val;
    }
  }

  // ---- barrier: wait for all 32 A1 blocks' delta(t0) adds ----
  if (tid == 0) {
    while (agent_load_u32(&bar[0]) < target) {
      __builtin_amdgcn_s_sleep(1);
    }
  }
  __syncthreads();

  if (bid < 32) {
    // ---- A2: edges of row t1 (skip accumulate at t1 == T-1) ----
    if (t1 < TSTEPS - 1) {
      const int e = t1 * NEDGE + (bid * 256 + tid);
      const int un = uv32u[e];
      const int vn = uv32v[e];
      const float w = wsc[e];
      const float xu = lazy3(xs64, dP, dA, un, ut0);
      const float xv = lazy3(xs64, dP, dA, vn, ut0);
      const int iv = __float2int_rn(w * (xv - xu));
      atomicAdd(&dB[un], (unsigned)iv);     // read next dispatch (boundary)
      atomicAdd(&dB[vn], (unsigned)(-iv));
    }
  } else {
    // ---- B2: apply endpoints of row t0 (tag-monotone pair write) ----
    const int j = (bid - 32) * 256 + tid;
    const int e2 = t0 * NEDGE + (j < NEDGE ? j : j - NEDGE);
    const int node = (j < NEDGE) ? uv32u[e2] : uv32v[e2];
    const float val = lazy3(xs64, dP, dA, node, ut0);
    pmax(&xs64[node], ((u64)(unsigned)t1 << 32) | (u64)__float_as_uint(val));
    cvals[(size_t)t0 * (2 * NEDGE) + j] = val;
  }
}

// ---------------------------------------------------------------------------
// k_resent: restore sentinel over ALL outX-tail scratch (uv32u/uv32v/wsc +
// the two scratch delta buffers), BEFORE k_scatter fills real values.
// ---------------------------------------------------------------------------
__global__ void k_resent(unsigned* __restrict__ outX32) {
  const int g = blockIdx.x * blockDim.x + threadIdx.x;
  const int total = 3 * TSTEPS * NEDGE + 2 * NNODE;
  for (int w = g; w < total; w += gridDim.x * blockDim.x) {
    outX32[NNODE + w] = SENT32;
  }
}

// ---------------------------------------------------------------------------
// k_scatter: compact -> dense, fully parallel; reads ORIGINAL u/v.
// ---------------------------------------------------------------------------
__global__ void k_scatter(const int* __restrict__ u, const int* __restrict__ v,
                          const float* __restrict__ cvals,
                          float* __restrict__ outX,
                          const unsigned* __restrict__ dflags) {
  const int g = blockIdx.x * blockDim.x + threadIdx.x;
  if (g >= (TSTEPS - 1) * 2 * NEDGE) return;
  const int is64 = (int)dflags[0];
  const int r = g / (2 * NEDGE);
  const int s = g - r * (2 * NEDGE);
  const int e = r * NEDGE + (s < NEDGE ? s : s - NEDGE);
  const int node = (s < NEDGE) ? edge_at(u, e, is64) : edge_at(v, e, is64);
  outX[(size_t)(r + 1) * NNODE + node] = cvals[g];
}

// ---------------------------------------------------------------------------
// k_fill: resolve sentinels by fill-forward; coalesced per-node columns.
// ---------------------------------------------------------------------------
__global__ void k_fill(const float* __restrict__ logit,
                       unsigned* __restrict__ outX32) {
  const int n = blockIdx.x * blockDim.x + threadIdx.x;
  if (n >= NNODE) return;
  unsigned carry = __float_as_uint(x0_of(logit, n));
  for (int t = 1; t < TSTEPS; ++t) {
    const size_t idx = (size_t)t * NNODE + n;
    const unsigned w = outX32[idx];
    if (w == SENT32) outX32[idx] = carry;
    else             carry = w;
  }
}

// ---------------------------------------------------------------------------
// k_kappa: parallel kappa from filled dense X; runs LAST (overwrites cvals).
// ---------------------------------------------------------------------------
__global__ void k_kappa(const int* __restrict__ u, const int* __restrict__ v,
                        const float* __restrict__ theta,
                        const float* __restrict__ X,
                        float* __restrict__ outKp, float* __restrict__ outKm,
                        const unsigned* __restrict__ dflags) {
  const int g = blockIdx.x * blockDim.x + threadIdx.x;
  const int is64 = (int)dflags[0];
  const int t  = g >> 13;
  const int un = edge_at(u, g, is64);
  const int vn = edge_at(v, g, is64);
  const float Xu = X[(size_t)t * NNODE + un];
  const float Xv = X[(size_t)t * NNODE + vn];
  const float ad = fabsf(Xu - Xv);
  const float epsp = sigm(theta[0]) * 0.5f;
  const float epsm = 0.5f + sigm(theta[1]) * 0.5f;
  outKp[g] = sigm(RHO_ * (epsp - ad));
  outKm[g] = sigm(RHO_ * (ad - epsm));
}

// ---------------------------------------------------------------------------
__global__ void kDiag(float* __restrict__ outX, int b0, int b1) {
  if (threadIdx.x != 0 || blockIdx.x != 0) return;
  outX[0] = (float)(2048 + 1024 * b0 + 512 * b1);
}

// ---------------------------------------------------------------------------
extern "C" void kernel_launch(void* const* d_in, const int* in_sizes, int n_in,
                              void* d_out, int out_size, void* d_ws, size_t ws_size,
                              hipStream_t stream) {
  const float* logit = (const float*)d_in[0];
  const float* theta = (const float*)d_in[1];
  const int*   u     = (const int*)d_in[2];
  const int*   v     = (const int*)d_in[3];
  const float* sp    = (const float*)d_in[4];
  const float* sm    = (const float*)d_in[5];

  float* outX  = (float*)d_out;                         // [T, N] f32
  float* outKp = outX + (size_t)TSTEPS * NNODE;
  float* outKm = outKp + (size_t)TSTEPS * NEDGE;

  // cvals scratch in kappa region; k_kappa runs last and overwrites it.
  float* cvals = outKp;

  // outX-tail scratch: ids + weights + 2 extra delta buffers (B3,B4).
  int*      uv32u = (int*)(outX + NNODE);
  int*      uv32v = uv32u + (size_t)TSTEPS * NEDGE;
  float*    wsc   = (float*)(uv32v + (size_t)TSTEPS * NEDGE);
  unsigned* b3    = (unsigned*)(wsc + (size_t)TSTEPS * NEDGE);
  unsigned* b4    = b3 + NNODE;

  const int c0 = (n_in == 6 &&
                  in_sizes[0] == NNODE && in_sizes[1] == 2 &&
                  in_sizes[2] == TSTEPS * NEDGE && in_sizes[3] == TSTEPS * NEDGE &&
                  in_sizes[4] == TSTEPS * NEDGE && in_sizes[5] == TSTEPS * NEDGE) ? 1 : 0;
  const size_t WS_NEED = (size_t)NNODE * 8 + (size_t)3 * NNODE * 4 + 64;
  const int c1 = (ws_size >= WS_NEED) ? 1 : 0;
  if (!c0 || !c1) {
    kDiag<<<1, 64, 0, stream>>>(outX, c0, c1);
    return;
  }

  // workspace: xs64 (N u64) | B0 | B1 | B2 (N u32 each) | dflags (8 u32)
  char* ws = (char*)d_ws;
  u64*      xs64   = (u64*)ws;
  unsigned* wb0    = (unsigned*)(ws + (size_t)NNODE * 8);
  unsigned* wb1    = (unsigned*)(ws + (size_t)NNODE * 8 + (size_t)NNODE * 4);
  unsigned* wb2    = (unsigned*)(ws + (size_t)NNODE * 8 + (size_t)2 * NNODE * 4);
  unsigned* dflags = (unsigned*)(ws + (size_t)NNODE * 8 + (size_t)3 * NNODE * 4);
  unsigned* bar    = dflags + 4;
  unsigned* B[5]   = {wb0, wb1, wb2, b3, b4};

  k_init<<<2048, 256, 0, stream>>>(logit, u, v, xs64, wb0, wb1, wb2, dflags,
                                   outX);
  k_prep<<<4096, 256, 0, stream>>>(u, v, sp, sm, uv32u, uv32v, wsc, b3, b4,
                                   dflags);

  for (int d = 0; d < TSTEPS / 2; ++d) {
    const int t0 = 2 * d;
    unsigned* dA  = B[t0 % 5];
    unsigned* dB  = B[(t0 + 1) % 5];
    unsigned* dP  = B[(t0 + 4) % 5];
    unsigned* dz1 = B[(t0 + 2) % 5];
    unsigned* dz2 = B[(t0 + 3) % 5];
    k_step2<<<160, 256, 0, stream>>>(uv32u, uv32v, wsc, xs64, dA, dB, dP,
                                     dz1, dz2, cvals, bar,
                                     (unsigned)(32 * (d + 1)), t0);
  }

  k_resent<<<4096, 256, 0, stream>>>((unsigned*)d_out);
  k_scatter<<<((TSTEPS - 1) * 2 * NEDGE + 255) / 256, 256, 0, stream>>>(
      u, v, cvals, outX, dflags);
  k_fill<<<(NNODE + 255) / 256, 256, 0, stream>>>(logit, (unsigned*)d_out);
  k_kappa<<<(TSTEPS * NEDGE) / 256, 256, 0, stream>>>(u, v, theta, outX,
                                                      outKp, outKm, dflags);
}

// Round 20
// 1477.012 us; speedup vs baseline: 1.2254x; 1.2254x over previous
//
#include <hip/hip_runtime.h>

// Problem constants (fixed by the reference).
#define TSTEPS 256
#define NNODE  100000
#define NEDGE  8192

constexpr float MU_P  = 0.1f;
constexpr float MU_M  = 0.05f;
constexpr float RHO_  = 16.0f;
constexpr float CLO   = 1e-5f;
constexpr float CHI   = 1.0f - 1e-5f;
constexpr float SCALE = 1048576.0f;          // 2^20 fixed-point for delta
constexpr float INVSC = 1.0f / 1048576.0f;

#define SENT32 0xFFFFFFFFu
typedef unsigned long long u64;

__device__ __forceinline__ float sigm(float x) {
  return 1.0f / (1.0f + __expf(-x));
}
__device__ __forceinline__ float x0_of(const float* logit, int n) {
  return fminf(fmaxf(sigm(logit[n]), CLO), CHI);
}
__device__ __forceinline__ int edge_at(const int* __restrict__ arr, int idx,
                                       int is64) {
  if (is64) return (int)((const long long*)arr)[idx];
  return arr[idx];
}
__device__ __forceinline__ u64 pload(const u64* p) {
  return __hip_atomic_load(p, __ATOMIC_RELAXED, __HIP_MEMORY_SCOPE_WORKGROUP);
}
__device__ __forceinline__ void pstore(u64* p, u64 v) {
  __hip_atomic_store(p, v, __ATOMIC_RELAXED, __HIP_MEMORY_SCOPE_WORKGROUP);
}
__device__ __forceinline__ float clipf(float x) {
  return fminf(fmaxf(x, CLO), CHI);
}

// R12/R15-proven lazy evaluator: pair + dprev loads issued in parallel;
// stale pair -> catch-up path reproduces the identical value (single tag
// per dispatch -> no write-ordering hazard; the R16-R18 trap needed two
// tags per dispatch and is gone with the single-step structure).
__device__ __forceinline__ float lazy2(const u64* xs64,
                                       const unsigned* __restrict__ dP,
                                       int n, unsigned t0) {
  const u64 a = pload(&xs64[n]);
  const int acc = (int)dP[n];
  const unsigned tag = (unsigned)(a >> 32);
  const float pv = __uint_as_float((unsigned)a);
  const float cu = clipf(pv + (float)acc * INVSC);
  return (tag == t0) ? pv : cu;
}

// ---------------------------------------------------------------------------
// k_init: pairs {tag0, clip(sigmoid)}; d0/d1/d2 zero; flags probe; outX row 0
// + sentinel rows 1..T-1. Re-runs every call -> deterministic replays.
// ---------------------------------------------------------------------------
__global__ void k_init(const float* __restrict__ logit,
                       const int* __restrict__ u, const int* __restrict__ v,
                       u64* __restrict__ xs64,
                       unsigned* __restrict__ d0, unsigned* __restrict__ d1,
                       unsigned* __restrict__ d2,
                       unsigned* __restrict__ dflags,
                       float* __restrict__ outX) {
  const int i = blockIdx.x * blockDim.x + threadIdx.x;
  const int stride = gridDim.x * blockDim.x;

  if (i == 0) {   // int width probe
    const unsigned* a = (const unsigned*)u;
    const unsigned* b = (const unsigned*)v;
    bool i64 = true;
    for (int k = 1; k < 128; k += 2) i64 = i64 && (a[k] == 0u) && (b[k] == 0u);
    dflags[0] = i64 ? 1u : 0u;
  }

  for (int n = i; n < NNODE; n += stride) {
    xs64[n] = (u64)__float_as_uint(x0_of(logit, n));   // tag 0
    d0[n] = 0u;
    d1[n] = 0u;
    d2[n] = 0u;
    outX[n] = sigm(logit[n]);            // row 0, unclipped, f32
  }
  unsigned* outX32 = (unsigned*)outX;
  const int total = TSTEPS * NNODE;
  for (int w = NNODE + i; w < total; w += stride) outX32[w] = SENT32;
}

// ---------------------------------------------------------------------------
// k_prep: packed int2 edge ids + premultiplied weights into outX-tail scratch
// (rows 1..63 of outX hold sentinel-garbage until post-passes; k_resent
// restores them). Removes is64 branch + sp/sm loads + one id load from the
// 256 serial dispatches.
// ---------------------------------------------------------------------------
__global__ void k_prep(const int* __restrict__ u, const int* __restrict__ v,
                       const float* __restrict__ sp, const float* __restrict__ sm,
                       int2* __restrict__ uvp, float* __restrict__ wsc,
                       const unsigned* __restrict__ dflags) {
  const int g = blockIdx.x * blockDim.x + threadIdx.x;
  const int stride = gridDim.x * blockDim.x;
  const int is64 = (int)dflags[0];
  for (int e = g; e < TSTEPS * NEDGE; e += stride) {
    uvp[e] = make_int2(edge_at(u, e, is64), edge_at(v, e, is64));
    wsc[e] = (MU_P * sp[e] - MU_M * sm[e]) * SCALE;
  }
}

// ---------------------------------------------------------------------------
// k_step (ONE dispatch per timestep t = the R15-proven structure; cross-step
// visibility = dispatch boundary, the cheapest cross-XCD sync on this part
// per R19's measurement). Role-partitioned 160 blocks x 256:
//   [0,32)  A: edge e=(t,i): iv = rn(wsc*(xv-xu)); atomicAdd dcur.
//   [32,96) B: apply endpoint slot j of row t-1: val = lazy2; pair {t,val};
//              cvals[(t-1)*2E+j] = val (coalesced).
//   [96,160)C: dense-zero dzero (next step's dcur; idle this dispatch).
// Host-side buffer rotation (no runtime-indexed pointer arrays, rule #20).
// ---------------------------------------------------------------------------
__global__ __launch_bounds__(256) void k_step(
    const int2* __restrict__ uvp, const float* __restrict__ wsc,
    u64* __restrict__ xs64,
    unsigned* __restrict__ dcur, const unsigned* __restrict__ dprev,
    unsigned* __restrict__ dzero,
    float* __restrict__ cvals, int t) {
  const int bid = blockIdx.x;
  const int tid = threadIdx.x;
  const unsigned ttag = (unsigned)t;

  if (bid < 32) {
    // ---- A: gather + accumulate (edges of row t) ----
    if (t < TSTEPS - 1) {
      const int e = t * NEDGE + bid * 256 + tid;
      const int2 p = uvp[e];
      const float w = wsc[e];
      const float xu = lazy2(xs64, dprev, p.x, ttag);
      const float xv = lazy2(xs64, dprev, p.y, ttag);
      const int iv = __float2int_rn(w * (xv - xu));
      atomicAdd(&dcur[p.x], (unsigned)iv);
      atomicAdd(&dcur[p.y], (unsigned)(-iv));
    }
  } else if (bid < 96) {
    // ---- B: apply endpoints of row t-1; persist pair + compact write ----
    if (t >= 1) {
      const int j = (bid - 32) * 256 + tid;     // 0..16383
      const int e2 = (t - 1) * NEDGE + (j < NEDGE ? j : j - NEDGE);
      const int2 p = uvp[e2];
      const int node = (j < NEDGE) ? p.x : p.y;
      const float val = lazy2(xs64, dprev, node, ttag);
      pstore(&xs64[node], ((u64)ttag << 32) | (u64)__float_as_uint(val));
      cvals[(size_t)(t - 1) * (2 * NEDGE) + j] = val;   // coalesced
    }
  } else {
    // ---- C: dense-zero the idle buffer (used next step as dcur) ----
    const int base = (bid - 96) * 256 + tid;
    for (int n = base; n < NNODE; n += 64 * 256) dzero[n] = 0u;
  }
}

// ---------------------------------------------------------------------------
// k_resent: restore sentinel over the outX-tail scratch (uvp + wsc = 3*T*E
// words), BEFORE k_scatter writes real values into those rows.
// ---------------------------------------------------------------------------
__global__ void k_resent(unsigned* __restrict__ outX32) {
  const int g = blockIdx.x * blockDim.x + threadIdx.x;
  const int total = 3 * TSTEPS * NEDGE;
  for (int w = g; w < total; w += gridDim.x * blockDim.x) {
    outX32[NNODE + w] = SENT32;
  }
}

// ---------------------------------------------------------------------------
// k_scatter: compact -> dense, fully parallel; reads ORIGINAL u/v (the
// packed scratch is mid-overwrite). Duplicates write identical bits.
// ---------------------------------------------------------------------------
__global__ void k_scatter(const int* __restrict__ u, const int* __restrict__ v,
                          const float* __restrict__ cvals,
                          float* __restrict__ outX,
                          const unsigned* __restrict__ dflags) {
  const int g = blockIdx.x * blockDim.x + threadIdx.x;
  if (g >= (TSTEPS - 1) * 2 * NEDGE) return;
  const int is64 = (int)dflags[0];
  const int r = g / (2 * NEDGE);
  const int s = g - r * (2 * NEDGE);
  const int e = r * NEDGE + (s < NEDGE ? s : s - NEDGE);
  const int node = (s < NEDGE) ? edge_at(u, e, is64) : edge_at(v, e, is64);
  outX[(size_t)(r + 1) * NNODE + node] = cvals[g];
}

// ---------------------------------------------------------------------------
// k_fill: fill-forward, BRANCHLESS + UNROLL-8 (R19 counters: old version ran
// 81us at 23.5% HBM peak, latency-bound at 1 load in flight). Unconditional
// reads AND writes: 8 independent loads in flight per thread; touched
// entries get rewritten with identical bits (benign). ~204 MB streaming.
// ---------------------------------------------------------------------------
__global__ void k_fill(const float* __restrict__ logit,
                       unsigned* __restrict__ outX32) {
  const int n = blockIdx.x * blockDim.x + threadIdx.x;
  if (n >= NNODE) return;
  unsigned carry = __float_as_uint(x0_of(logit, n));   // untouched = clip(X0)

  int t = 1;
  for (; t + 8 <= TSTEPS; t += 8) {
    const size_t base = (size_t)t * NNODE + n;
    unsigned w0 = outX32[base];
    unsigned w1 = outX32[base + (size_t)NNODE];
    unsigned w2 = outX32[base + (size_t)2 * NNODE];
    unsigned w3 = outX32[base + (size_t)3 * NNODE];
    unsigned w4 = outX32[base + (size_t)4 * NNODE];
    unsigned w5 = outX32[base + (size_t)5 * NNODE];
    unsigned w6 = outX32[base + (size_t)6 * NNODE];
    unsigned w7 = outX32[base + (size_t)7 * NNODE];
    w0 = (w0 == SENT32) ? carry : w0;
    w1 = (w1 == SENT32) ? w0 : w1;
    w2 = (w2 == SENT32) ? w1 : w2;
    w3 = (w3 == SENT32) ? w2 : w3;
    w4 = (w4 == SENT32) ? w3 : w4;
    w5 = (w5 == SENT32) ? w4 : w5;
    w6 = (w6 == SENT32) ? w5 : w6;
    w7 = (w7 == SENT32) ? w6 : w7;
    carry = w7;
    outX32[base]                     = w0;
    outX32[base + (size_t)NNODE]     = w1;
    outX32[base + (size_t)2 * NNODE] = w2;
    outX32[base + (size_t)3 * NNODE] = w3;
    outX32[base + (size_t)4 * NNODE] = w4;
    outX32[base + (size_t)5 * NNODE] = w5;
    outX32[base + (size_t)6 * NNODE] = w6;
    outX32[base + (size_t)7 * NNODE] = w7;
  }
  for (; t < TSTEPS; ++t) {
    const size_t idx = (size_t)t * NNODE + n;
    const unsigned w = outX32[idx];
    const unsigned r = (w == SENT32) ? carry : w;
    carry = r;
    outX32[idx] = r;
  }
}

// ---------------------------------------------------------------------------
// k_kappa: parallel kappa from the filled dense X; runs LAST (overwrites the
// kappa region that temporarily held cvals).
// ---------------------------------------------------------------------------
__global__ void k_kappa(const int* __restrict__ u, const int* __restrict__ v,
                        const float* __restrict__ theta,
                        const float* __restrict__ X,
                        float* __restrict__ outKp, float* __restrict__ outKm,
                        const unsigned* __restrict__ dflags) {
  const int g = blockIdx.x * blockDim.x + threadIdx.x;
  const int is64 = (int)dflags[0];
  const int t  = g >> 13;
  const int un = edge_at(u, g, is64);
  const int vn = edge_at(v, g, is64);
  const float Xu = X[(size_t)t * NNODE + un];
  const float Xv = X[(size_t)t * NNODE + vn];
  const float ad = fabsf(Xu - Xv);
  const float epsp = sigm(theta[0]) * 0.5f;
  const float epsm = 0.5f + sigm(theta[1]) * 0.5f;
  outKp[g] = sigm(RHO_ * (epsp - ad));
  outKm[g] = sigm(RHO_ * (ad - epsm));
}

// ---------------------------------------------------------------------------
__global__ void kDiag(float* __restrict__ outX, int b0, int b1) {
  if (threadIdx.x != 0 || blockIdx.x != 0) return;
  outX[0] = (float)(2048 + 1024 * b0 + 512 * b1);
}

// ---------------------------------------------------------------------------
extern "C" void kernel_launch(void* const* d_in, const int* in_sizes, int n_in,
                              void* d_out, int out_size, void* d_ws, size_t ws_size,
                              hipStream_t stream) {
  const float* logit = (const float*)d_in[0];
  const float* theta = (const float*)d_in[1];
  const int*   u     = (const int*)d_in[2];
  const int*   v     = (const int*)d_in[3];
  const float* sp    = (const float*)d_in[4];
  const float* sm    = (const float*)d_in[5];

  float* outX  = (float*)d_out;                         // [T, N] f32
  float* outKp = outX + (size_t)TSTEPS * NNODE;
  float* outKm = outKp + (size_t)TSTEPS * NEDGE;

  // cvals scratch: spans outKp+outKm (16.71 <= 16.78 MB); k_kappa runs last.
  float* cvals = outKp;

  // outX-tail scratch: packed ids (2*T*E) + weights (T*E) = 25.2 MB.
  int2*  uvp = (int2*)(outX + NNODE);
  float* wsc = (float*)(uvp + (size_t)TSTEPS * NEDGE);

  const int c0 = (n_in == 6 &&
                  in_sizes[0] == NNODE && in_sizes[1] == 2 &&
                  in_sizes[2] == TSTEPS * NEDGE && in_sizes[3] == TSTEPS * NEDGE &&
                  in_sizes[4] == TSTEPS * NEDGE && in_sizes[5] == TSTEPS * NEDGE) ? 1 : 0;
  const size_t WS_NEED = (size_t)NNODE * 8 + (size_t)3 * NNODE * 4 + 64;
  const int c1 = (ws_size >= WS_NEED) ? 1 : 0;
  if (!c0 || !c1) {
    kDiag<<<1, 64, 0, stream>>>(outX, c0, c1);
    return;
  }

  // workspace: xs64 (N u64) | d0 | d1 | d2 (N u32 each) | dflags (8 u32)
  char* ws = (char*)d_ws;
  u64*      xs64   = (u64*)ws;
  unsigned* d0     = (unsigned*)(ws + (size_t)NNODE * 8);
  unsigned* d1     = (unsigned*)(ws + (size_t)NNODE * 8 + (size_t)NNODE * 4);
  unsigned* d2     = (unsigned*)(ws + (size_t)NNODE * 8 + (size_t)2 * NNODE * 4);
  unsigned* dflags = (unsigned*)(ws + (size_t)NNODE * 8 + (size_t)3 * NNODE * 4);
  unsigned* B[3]   = {d0, d1, d2};

  k_init<<<2048, 256, 0, stream>>>(logit, u, v, xs64, d0, d1, d2, dflags, outX);
  k_prep<<<4096, 256, 0, stream>>>(u, v, sp, sm, uvp, wsc, dflags);

  for (int t = 0; t < TSTEPS; ++t) {
    unsigned* dcur  = B[t % 3];
    unsigned* dprev = B[(t + 2) % 3];
    unsigned* dzero = B[(t + 1) % 3];
    k_step<<<160, 256, 0, stream>>>(uvp, wsc, xs64, dcur, dprev, dzero,
                                    cvals, t);
  }

  k_resent<<<4096, 256, 0, stream>>>((unsigned*)d_out);
  k_scatter<<<((TSTEPS - 1) * 2 * NEDGE + 255) / 256, 256, 0, stream>>>(
      u, v, cvals, outX, dflags);
  k_fill<<<(NNODE + 255) / 256, 256, 0, stream>>>(logit, (unsigned*)d_out);
  k_kappa<<<(TSTEPS * NEDGE) / 256, 256, 0, stream>>>(u, v, theta, outX,
                                                      outKp, outKm, dflags);
}